// Round 8
// baseline (90.400 us; speedup 1.0000x reference)
//
#include <hip/hip_runtime.h>

// PathEncoder: out[b,x,y,h] = sum_l dot(edata[b, path[b,x,y,l], :], emb[l,h,:]) / clip(dist,1,4)
// Two passes, bf16 intermediate table:
//  Pass 1 (proj_kernel): proj[b,e,j] = dot(edge_feat[b,e,:], W[j,:]) fp32, stored bf16 RNE.
//     W read at wave-uniform global addresses -> scalarized s_load (K$) or broadcast L1 hit;
//     NO LDS (LDS broadcast was issue-bound: 512 ds_read_b128/thread x 12cyc ~ 10us).
//     Blocks mapped b = blockIdx&15 so graph b's proj slice is WRITTEN on XCD b&7 --
//     the same XCD pass 2 reads it from (warm local L2, no cross-XCD first-touch miss).
//  Pass 2 (gather_kernel): out[gid,h] = (1/denom) * sum_l proj_bf16[b, path_l, l*8+h].
//     16 B gather per path element; 262 KB/graph slice, L2-resident, XCD-pinned.

#define E_DIM 4096
#define D_DIM 64
#define L_DIM 4
#define H_DIM 8
#define LH 32                   // L*H
#define B_DIM 16
#define NN 16384                // N*N
#define ROWS_PER_B (E_DIM + 1)  // 4097 (includes zero pad row)

typedef float f32x4 __attribute__((ext_vector_type(4)));
typedef int   i32x4 __attribute__((ext_vector_type(4)));
typedef unsigned int u32;

__device__ __forceinline__ u32 f32_bits(float f) { return __builtin_bit_cast(u32, f); }
__device__ __forceinline__ float bits_f32(u32 u) { return __builtin_bit_cast(float, u); }

// round-to-nearest-even f32 -> bf16 (low 16 bits)
__device__ __forceinline__ u32 f2bf(float f) {
    u32 x = f32_bits(f);
    return (x + 0x7fffu + ((x >> 16) & 1u)) >> 16;
}

// ---------------- Pass 1: per-edge projection (fp32 math, bf16 store) ------
// grid: 272 blocks = 17 chunks x 16 graphs; block handles 256 consecutive rows
// of one graph. blockIdx = chunk*16 + b  ->  XCD (blockIdx%8) == b%8 for all chunks.
__global__ __launch_bounds__(256) void proj_kernel(
    const float* __restrict__ edge_feat,   // [B, E, 64]
    const float* __restrict__ W,           // [32, 64]
    unsigned short* __restrict__ proj)     // [B, E+1, 32] bf16
{
    const int b     = blockIdx.x & 15;
    const int chunk = blockIdx.x >> 4;               // 0..16
    const int e     = chunk * 256 + threadIdx.x;     // 0..4351
    if (e > E_DIM) return;
    const int r = b * ROWS_PER_B + e;

    i32x4* outp = (i32x4*)(proj + (size_t)r * LH);   // 64 B = 4 x int4

    if (e == E_DIM) {                                // zero pad row
        i32x4 z = (i32x4)0;
        #pragma unroll
        for (int q = 0; q < 4; ++q) outp[q] = z;
        return;
    }

    const f32x4* row4 = (const f32x4*)(edge_feat + ((size_t)b * E_DIM + e) * D_DIM);
    f32x4 row[16];
    #pragma unroll
    for (int i = 0; i < 16; ++i) row[i] = row4[i];

    const f32x4* W4 = (const f32x4*)W;               // [32][16] f32x4, wave-uniform reads

    u32 packed[16];                                  // 32 bf16 as 16 u32 pairs
    for (int jq = 0; jq < 8; ++jq) {                 // 4 outputs per iter
        float tmp[4];
        #pragma unroll
        for (int jj = 0; jj < 4; ++jj) {
            const int j = jq * 4 + jj;
            f32x4 acc = (f32x4)0.f;
            #pragma unroll
            for (int d4 = 0; d4 < 16; ++d4) {
                acc += row[d4] * W4[j * 16 + d4];    // uniform -> s_load / L1 broadcast
            }
            tmp[jj] = (acc.x + acc.y) + (acc.z + acc.w);
        }
        packed[jq * 2]     = f2bf(tmp[0]) | (f2bf(tmp[1]) << 16);
        packed[jq * 2 + 1] = f2bf(tmp[2]) | (f2bf(tmp[3]) << 16);
    }
    #pragma unroll
    for (int q = 0; q < 4; ++q) {
        i32x4 v = { (int)packed[q*4], (int)packed[q*4+1], (int)packed[q*4+2], (int)packed[q*4+3] };
        outp[q] = v;
    }
}

// ---------------- Pass 2: gather + sum + scale ----------------
__global__ __launch_bounds__(256) void gather_kernel(
    const i32x4* __restrict__ path4,       // [B*N*N] int4 (L=4 packed)
    const int*  __restrict__ dist,         // [B*N*N]
    const unsigned short* __restrict__ proj, // [B, E+1, 32] bf16
    float* __restrict__ out)               // [B*N*N, 8]
{
    const int tid   = threadIdx.x;
    const int blk   = blockIdx.x;          // 1024 blocks
    const int b     = blk & 15;            // graph b pinned to XCD b&7 (matches pass 1)
    const int chunk = blk >> 4;
    const int gid   = (b << 14) | (chunk << 8) | tid;

    i32x4 p = __builtin_nontemporal_load(path4 + gid);
    int  dv = __builtin_nontemporal_load(dist + gid);

    const unsigned short* pb = proj + (size_t)b * ROWS_PER_B * LH;

    // l-th gather: 8 bf16 (16 B) at row path_l, cols l*8..l*8+7 (warm local L2)
    i32x4 A = *(const i32x4*)(pb + (u32)p.x * LH + 0);
    i32x4 Bv= *(const i32x4*)(pb + (u32)p.y * LH + 8);
    i32x4 C = *(const i32x4*)(pb + (u32)p.z * LH + 16);
    i32x4 D = *(const i32x4*)(pb + (u32)p.w * LH + 24);

    dv = dv < 1 ? 1 : (dv > L_DIM ? L_DIM : dv);
    float s = 1.0f / (float)dv;            // exact for 1,2,4; ~1ulp for 3

    float oo[8];
    #pragma unroll
    for (int k = 0; k < 4; ++k) {
        u32 a = (u32)A[k], bb = (u32)Bv[k], c = (u32)C[k], d = (u32)D[k];
        float fe = (bits_f32(a << 16) + bits_f32(bb << 16))
                 + (bits_f32(c << 16) + bits_f32(d << 16));
        float fo = (bits_f32(a & 0xffff0000u) + bits_f32(bb & 0xffff0000u))
                 + (bits_f32(c & 0xffff0000u) + bits_f32(d & 0xffff0000u));
        oo[2*k]   = fe * s;
        oo[2*k+1] = fo * s;
    }
    f32x4 o0 = { oo[0], oo[1], oo[2], oo[3] };
    f32x4 o1 = { oo[4], oo[5], oo[6], oo[7] };

    f32x4* op = (f32x4*)(out + (size_t)gid * 8);
    __builtin_nontemporal_store(o0, op);
    __builtin_nontemporal_store(o1, op + 1);
}

extern "C" void kernel_launch(void* const* d_in, const int* in_sizes, int n_in,
                              void* d_out, int out_size, void* d_ws, size_t ws_size,
                              hipStream_t stream) {
    const float* edge_feat = (const float*)d_in[0];   // [16,4096,64] f32
    const int*   path      = (const int*)  d_in[1];   // [16,128,128,4] i32
    const int*   dist      = (const int*)  d_in[2];   // [16,128,128] i32
    const float* emb_w     = (const float*)d_in[3];   // [32,64] f32

    unsigned short* proj = (unsigned short*)d_ws;     // [16,4097,32] bf16 = 4.2 MB

    // 17 chunks of 256 rows cover 4097 rows; 16 graphs interleaved for XCD alignment
    proj_kernel<<<17 * B_DIM, 256, 0, stream>>>(edge_feat, emb_w, proj);

    gather_kernel<<<(B_DIM * NN) / 256, 256, 0, stream>>>(
        (const i32x4*)path, dist, proj, (float*)d_out);
}

// Round 9
// 85.461 us; speedup vs baseline: 1.0578x; 1.0578x over previous
//
#include <hip/hip_runtime.h>

// PathEncoder: out[b,x,y,h] = sum_l dot(edata[b, path[b,x,y,l], :], emb[l,h,:]) / clip(dist,1,4)
// Two passes, bf16 intermediate table:
//  Pass 1 (proj_kernel): proj[b,e,j] = dot(edge_feat[b,e,:], W[j,:]) fp32, stored bf16 RNE.
//     W staged in LDS (8 KB); all 64 lanes read the same address -> conflict-free broadcast.
//     (Round-8 data: global wave-uniform W reads were SLOWER (90.4 vs 84.0) -- compiler
//      did not scalarize; 512 per-lane L1 broadcasts lost to 512 ds_read_b128. Reverted.)
//     Blocks mapped b = blockIdx&15 so graph b's slice is written on the XCD that reads it.
//  Pass 2 (gather_kernel): out[gid,h] = (1/denom) * sum_l proj_bf16[b, path_l, l*8+h].
//     2 pixels per thread: 8 independent 16 B gathers in flight (2x MLP), half the waves.
//     XCD-locality: b = blockIdx&15 pins each graph's 262 KB slice (b, b+8 share an XCD).

#define E_DIM 4096
#define D_DIM 64
#define L_DIM 4
#define H_DIM 8
#define LH 32                   // L*H
#define B_DIM 16
#define NN 16384                // N*N
#define ROWS_PER_B (E_DIM + 1)  // 4097 (includes zero pad row)

typedef float f32x4 __attribute__((ext_vector_type(4)));
typedef int   i32x4 __attribute__((ext_vector_type(4)));
typedef unsigned int u32;

__device__ __forceinline__ u32 f32_bits(float f) { return __builtin_bit_cast(u32, f); }
__device__ __forceinline__ float bits_f32(u32 u) { return __builtin_bit_cast(float, u); }

// round-to-nearest-even f32 -> bf16 (low 16 bits)
__device__ __forceinline__ u32 f2bf(float f) {
    u32 x = f32_bits(f);
    return (x + 0x7fffu + ((x >> 16) & 1u)) >> 16;
}

// ---------------- Pass 1: per-edge projection (fp32 math, bf16 store) ------
// grid: 272 blocks = 17 chunks x 16 graphs; block handles 256 consecutive rows
// of one graph. blockIdx = chunk*16 + b  ->  XCD (blockIdx%8) == b%8 for all chunks.
__global__ __launch_bounds__(256) void proj_kernel(
    const float* __restrict__ edge_feat,   // [B, E, 64]
    const float* __restrict__ W,           // [32, 64]
    unsigned short* __restrict__ proj)     // [B, E+1, 32] bf16
{
    __shared__ f32x4 Wl[LH * 16];          // 32 rows x 16 float4 = 8 KB

    const int tid = threadIdx.x;
    const f32x4* W4 = (const f32x4*)W;     // 512 float4 total
    Wl[tid]       = W4[tid];
    Wl[tid + 256] = W4[tid + 256];
    __syncthreads();

    const int b     = blockIdx.x & 15;
    const int chunk = blockIdx.x >> 4;               // 0..16
    const int e     = chunk * 256 + tid;             // 0..4351
    if (e > E_DIM) return;
    const int r = b * ROWS_PER_B + e;

    i32x4* outp = (i32x4*)(proj + (size_t)r * LH);   // 64 B = 4 x int4

    if (e == E_DIM) {                                // zero pad row
        i32x4 z = (i32x4)0;
        #pragma unroll
        for (int q = 0; q < 4; ++q) outp[q] = z;
        return;
    }

    const f32x4* row4 = (const f32x4*)(edge_feat + ((size_t)b * E_DIM + e) * D_DIM);
    f32x4 row[16];
    #pragma unroll
    for (int i = 0; i < 16; ++i) row[i] = row4[i];

    u32 packed[16];                                  // 32 bf16 as 16 u32 pairs
    for (int jq = 0; jq < 8; ++jq) {                 // 4 outputs per iter
        float tmp[4];
        #pragma unroll
        for (int jj = 0; jj < 4; ++jj) {
            const int j = jq * 4 + jj;
            f32x4 acc = (f32x4)0.f;
            #pragma unroll
            for (int d4 = 0; d4 < 16; ++d4) {
                acc += row[d4] * Wl[j * 16 + d4];    // same-addr LDS broadcast, conflict-free
            }
            tmp[jj] = (acc.x + acc.y) + (acc.z + acc.w);
        }
        packed[jq * 2]     = f2bf(tmp[0]) | (f2bf(tmp[1]) << 16);
        packed[jq * 2 + 1] = f2bf(tmp[2]) | (f2bf(tmp[3]) << 16);
    }
    #pragma unroll
    for (int q = 0; q < 4; ++q) {
        i32x4 v = { (int)packed[q*4], (int)packed[q*4+1], (int)packed[q*4+2], (int)packed[q*4+3] };
        outp[q] = v;
    }
}

// ---------------- Pass 2: gather + sum + scale (2 pixels/thread) -----------
__global__ __launch_bounds__(256) void gather_kernel(
    const i32x4* __restrict__ path4,       // [B*N*N] int4 (L=4 packed)
    const int*  __restrict__ dist,         // [B*N*N]
    const unsigned short* __restrict__ proj, // [B, E+1, 32] bf16
    float* __restrict__ out)               // [B*N*N, 8]
{
    const int tid   = threadIdx.x;
    const int blk   = blockIdx.x;          // 512 blocks
    const int b     = blk & 15;            // graph b pinned to XCD b&7 (matches pass 1)
    const int chunk = blk >> 4;            // 0..31
    const int g0    = (b << 14) | (chunk << 9) | tid;   // pixel 0
    const int g1    = g0 + 256;                          // pixel 1

    // issue all independent loads up front (8 gathers + 2 path + 2 dist in flight)
    i32x4 p0 = __builtin_nontemporal_load(path4 + g0);
    i32x4 p1 = __builtin_nontemporal_load(path4 + g1);
    int  dv0 = __builtin_nontemporal_load(dist + g0);
    int  dv1 = __builtin_nontemporal_load(dist + g1);

    const unsigned short* pb = proj + (size_t)b * ROWS_PER_B * LH;

    i32x4 A0 = *(const i32x4*)(pb + (u32)p0.x * LH + 0);
    i32x4 B0 = *(const i32x4*)(pb + (u32)p0.y * LH + 8);
    i32x4 C0 = *(const i32x4*)(pb + (u32)p0.z * LH + 16);
    i32x4 D0 = *(const i32x4*)(pb + (u32)p0.w * LH + 24);
    i32x4 A1 = *(const i32x4*)(pb + (u32)p1.x * LH + 0);
    i32x4 B1 = *(const i32x4*)(pb + (u32)p1.y * LH + 8);
    i32x4 C1 = *(const i32x4*)(pb + (u32)p1.z * LH + 16);
    i32x4 D1 = *(const i32x4*)(pb + (u32)p1.w * LH + 24);

    dv0 = dv0 < 1 ? 1 : (dv0 > L_DIM ? L_DIM : dv0);
    dv1 = dv1 < 1 ? 1 : (dv1 > L_DIM ? L_DIM : dv1);
    float s0 = 1.0f / (float)dv0;          // exact for 1,2,4; ~1ulp for 3
    float s1 = 1.0f / (float)dv1;

    float oo[8];
    #pragma unroll
    for (int k = 0; k < 4; ++k) {
        u32 a = (u32)A0[k], bb = (u32)B0[k], c = (u32)C0[k], d = (u32)D0[k];
        float fe = (bits_f32(a << 16) + bits_f32(bb << 16))
                 + (bits_f32(c << 16) + bits_f32(d << 16));
        float fo = (bits_f32(a & 0xffff0000u) + bits_f32(bb & 0xffff0000u))
                 + (bits_f32(c & 0xffff0000u) + bits_f32(d & 0xffff0000u));
        oo[2*k]   = fe * s0;
        oo[2*k+1] = fo * s0;
    }
    f32x4 o0 = { oo[0], oo[1], oo[2], oo[3] };
    f32x4 o1 = { oo[4], oo[5], oo[6], oo[7] };
    f32x4* op0 = (f32x4*)(out + (size_t)g0 * 8);
    __builtin_nontemporal_store(o0, op0);
    __builtin_nontemporal_store(o1, op0 + 1);

    #pragma unroll
    for (int k = 0; k < 4; ++k) {
        u32 a = (u32)A1[k], bb = (u32)B1[k], c = (u32)C1[k], d = (u32)D1[k];
        float fe = (bits_f32(a << 16) + bits_f32(bb << 16))
                 + (bits_f32(c << 16) + bits_f32(d << 16));
        float fo = (bits_f32(a & 0xffff0000u) + bits_f32(bb & 0xffff0000u))
                 + (bits_f32(c & 0xffff0000u) + bits_f32(d & 0xffff0000u));
        oo[2*k]   = fe * s1;
        oo[2*k+1] = fo * s1;
    }
    f32x4 o2 = { oo[0], oo[1], oo[2], oo[3] };
    f32x4 o3 = { oo[4], oo[5], oo[6], oo[7] };
    f32x4* op1 = (f32x4*)(out + (size_t)g1 * 8);
    __builtin_nontemporal_store(o2, op1);
    __builtin_nontemporal_store(o3, op1 + 1);
}

extern "C" void kernel_launch(void* const* d_in, const int* in_sizes, int n_in,
                              void* d_out, int out_size, void* d_ws, size_t ws_size,
                              hipStream_t stream) {
    const float* edge_feat = (const float*)d_in[0];   // [16,4096,64] f32
    const int*   path      = (const int*)  d_in[1];   // [16,128,128,4] i32
    const int*   dist      = (const int*)  d_in[2];   // [16,128,128] i32
    const float* emb_w     = (const float*)d_in[3];   // [32,64] f32

    unsigned short* proj = (unsigned short*)d_ws;     // [16,4097,32] bf16 = 4.2 MB

    // 17 chunks of 256 rows cover 4097 rows; 16 graphs interleaved for XCD alignment
    proj_kernel<<<17 * B_DIM, 256, 0, stream>>>(edge_feat, emb_w, proj);

    // 512 blocks: 2 pixels per thread
    gather_kernel<<<(B_DIM * NN) / 512, 256, 0, stream>>>(
        (const i32x4*)path, dist, proj, (float*)d_out);
}